// Round 1
// baseline (399.611 us; speedup 1.0000x reference)
//
#include <hip/hip_runtime.h>
#include <stdint.h>

typedef __attribute__((ext_vector_type(4))) int v4i;

#define BATCH 8192
#define KDIM  4096
#define NOUT  4096

// pack x: fp32 -> i8 {1,0}  (x>0 -> 1 else 0), 4 elems/thread
__global__ __launch_bounds__(256) void pack_x(const float* __restrict__ x,
                                              uint32_t* __restrict__ xb) {
    int t = blockIdx.x * 256 + threadIdx.x;
    float4 f = ((const float4*)x)[t];
    uint32_t b = (f.x > 0.f ? 1u : 0u)
               | ((f.y > 0.f ? 1u : 0u) << 8)
               | ((f.z > 0.f ? 1u : 0u) << 16)
               | ((f.w > 0.f ? 1u : 0u) << 24);
    xb[t] = b;
}

// pack W: fp32 -> i8 {+1,-1}  (W>0 -> +1 else -1), 4 elems/thread
__global__ __launch_bounds__(256) void pack_w(const float* __restrict__ w,
                                              uint32_t* __restrict__ wb) {
    int t = blockIdx.x * 256 + threadIdx.x;
    float4 f = ((const float4*)w)[t];
    uint32_t b = (f.x > 0.f ? 0x01u : 0xFFu)
               | ((f.y > 0.f ? 0x01u : 0xFFu) << 8)
               | ((f.z > 0.f ? 0x01u : 0xFFu) << 16)
               | ((f.w > 0.f ? 0x01u : 0xFFu) << 24);
    wb[t] = b;
}

// C[M,N] = A[M,K] * B[N,K]^T, i8 inputs, f32 out (values integer-exact).
// m97 structure: 128x128 block tile, BK=64, 4 waves (2x2 of 64x64),
// global_load_lds width-16 staging, 16x16x64 i8 MFMA, 4x4 acc tiles/wave.
// LDS chunk placement XOR-swizzled via the GLOBAL fetch address
// (global_load_lds forces lds dst = base + lane*16).
__global__ __launch_bounds__(256) void bin_gemm(const int8_t* __restrict__ A,
                                                const int8_t* __restrict__ B,
                                                float* __restrict__ C) {
    __shared__ __align__(16) int8_t smA[128 * 64];
    __shared__ __align__(16) int8_t smB[128 * 64];

    const int tid  = threadIdx.x;
    const int w    = tid >> 6;          // wave 0..3
    const int lane = tid & 63;
    const int q    = lane >> 4;         // quad 0..3
    const int mp   = lane & 15;

    const int Mbase = blockIdx.y * 128;
    const int Nbase = blockIdx.x * 128;
    const int wm = (w >> 1) * 64;       // wave M offset in tile
    const int wn = (w & 1) * 64;        // wave N offset in tile

    // Staging: each wave stages two 16-row groups for A and for B.
    // lane i covers row i/4, chunk i%4 of a 16x64B group; fetch the
    // swizzled global chunk c = (i&3) ^ ((row>>1)&3) = (i&3)^((i>>3)&3).
    const int srow = lane >> 2;
    const int swz  = ((lane & 3) ^ ((lane >> 3) & 3)) * 16;
    const int g0   = (w * 2 + 0) * 16;
    const int g1   = (w * 2 + 1) * 16;

    const int8_t* gA0 = A + (size_t)(Mbase + g0 + srow) * KDIM + swz;
    const int8_t* gA1 = A + (size_t)(Mbase + g1 + srow) * KDIM + swz;
    const int8_t* gB0 = B + (size_t)(Nbase + g0 + srow) * KDIM + swz;
    const int8_t* gB1 = B + (size_t)(Nbase + g1 + srow) * KDIM + swz;

    auto lA0 = (__attribute__((address_space(3))) void*)(smA + g0 * 64);
    auto lA1 = (__attribute__((address_space(3))) void*)(smA + g1 * 64);
    auto lB0 = (__attribute__((address_space(3))) void*)(smB + g0 * 64);
    auto lB1 = (__attribute__((address_space(3))) void*)(smB + g1 * 64);

    // Fragment read: A[m=mp][k=q*16..+16) lives at row*64 + swizzled slot.
    const int slot = (q ^ ((mp >> 1) & 3)) * 16;

    v4i acc[4][4] = {};

    for (int kt = 0; kt < KDIM / 64; ++kt) {
        const int kof = kt * 64;
        __builtin_amdgcn_global_load_lds(
            (__attribute__((address_space(1))) void*)(gA0 + kof), lA0, 16, 0, 0);
        __builtin_amdgcn_global_load_lds(
            (__attribute__((address_space(1))) void*)(gA1 + kof), lA1, 16, 0, 0);
        __builtin_amdgcn_global_load_lds(
            (__attribute__((address_space(1))) void*)(gB0 + kof), lB0, 16, 0, 0);
        __builtin_amdgcn_global_load_lds(
            (__attribute__((address_space(1))) void*)(gB1 + kof), lB1, 16, 0, 0);
        __syncthreads();   // compiler emits vmcnt(0) drain before s_barrier

        v4i af[4], bf[4];
        #pragma unroll
        for (int i = 0; i < 4; ++i)
            af[i] = *(const v4i*)(smA + (wm + i * 16 + mp) * 64 + slot);
        #pragma unroll
        for (int i = 0; i < 4; ++i)
            bf[i] = *(const v4i*)(smB + (wn + i * 16 + mp) * 64 + slot);

        #pragma unroll
        for (int mi = 0; mi < 4; ++mi)
            #pragma unroll
            for (int ni = 0; ni < 4; ++ni)
                acc[mi][ni] = __builtin_amdgcn_mfma_i32_16x16x64_i8(
                    af[mi], bf[ni], acc[mi][ni], 0, 0, 0);
        __syncthreads();   // all waves done reading before next overwrite
    }

    // C/D layout: col = lane&15, row = quad*4 + reg (shape-determined).
    float* Cp = C + (size_t)(Mbase + wm + q * 4) * NOUT + (Nbase + wn + mp);
    #pragma unroll
    for (int mi = 0; mi < 4; ++mi)
        #pragma unroll
        for (int ni = 0; ni < 4; ++ni)
            #pragma unroll
            for (int r = 0; r < 4; ++r)
                Cp[(size_t)(mi * 16 + r) * NOUT + ni * 16] = (float)acc[mi][ni][r];
}

extern "C" void kernel_launch(void* const* d_in, const int* in_sizes, int n_in,
                              void* d_out, int out_size, void* d_ws, size_t ws_size,
                              hipStream_t stream) {
    const float* x = (const float*)d_in[0];   // [8192, 4096] f32
    const float* W = (const float*)d_in[1];   // [4096, 4096] f32, values +/-1
    float* out = (float*)d_out;               // [8192, 4096] f32

    int8_t* xb = (int8_t*)d_ws;                           // 32 MiB
    int8_t* wb = (int8_t*)d_ws + (size_t)BATCH * KDIM;    // 16 MiB  (needs 48 MiB ws)

    pack_x<<<(BATCH * (size_t)KDIM / 4) / 256, 256, 0, stream>>>(x, (uint32_t*)xb);
    pack_w<<<((size_t)NOUT * KDIM / 4) / 256, 256, 0, stream>>>(W, (uint32_t*)wb);

    dim3 grid(NOUT / 128, BATCH / 128);   // (32, 64) = 2048 blocks
    bin_gemm<<<grid, 256, 0, stream>>>(xb, wb, out);
}